// Round 8
// baseline (250.450 us; speedup 1.0000x reference)
//
#include <hip/hip_runtime.h>
#include <hip/hip_bf16.h>

typedef short bf16x8 __attribute__((ext_vector_type(8)));
typedef float f32x16 __attribute__((ext_vector_type(16)));
typedef unsigned short u16;

#define B 128
#define LQ 32
#define LK 128
#define D 128
#define YPB 4
#define NBLK 512

// ws layout:
//   lbf : fragment-ordered l, [x][ks(8)][hh(2)][rr(32)] x 16B          (1 MiB @ 0)
//   rbf : fragment-ordered r, [y][mj(4)][ks(8)][hh(2)][rr(32)] x 16B   (4 MiB @ 1M)
//   sims: B*B f32 (64 KiB @ 5M)
//   sync: 2 counters (@ 5M + 64K), memset to 0 each call
// 32x32x16 MFMA fragment: lane = hh*32 + rr holds 8 elems, k = ks*16+hh*8+e;
// rr = A-row / B-col. Verified rounds 3-5 (absmax 0).

static __device__ inline u16 f2bf_rne(float f) {
  union { float f; unsigned u; } v; v.f = f;
  unsigned r = v.u + 0x7fffu + ((v.u >> 16) & 1u);
  return (u16)(r >> 16);
}

// Device-scope grid barrier. Safe: all NBLK blocks co-resident
// (2 blocks/CU x 256 CUs, launch_bounds caps VGPR, ~no LDS).
static __device__ inline void gbar(unsigned* c, unsigned tgt) {
  __threadfence();                       // release this thread's writes
  __syncthreads();                       // whole block reached the fence
  if (threadIdx.x == 0) {
    atomicAdd(c, 1u);
    while (atomicAdd(c, 0u) < tgt) __builtin_amdgcn_s_sleep(1);
  }
  __syncthreads();
  __threadfence();                       // acquire before reading others' data
}

__global__ __launch_bounds__(256, 2) void fused_kernel(
    const float* __restrict__ left, const float* __restrict__ right,
    const float* __restrict__ ls, const int* __restrict__ pos,
    float* __restrict__ out, char* __restrict__ lbf, char* __restrict__ rbf,
    float* __restrict__ sims, unsigned* __restrict__ syncp) {
  __shared__ float shred[4];
  const int tid  = threadIdx.x;
  const int lane = tid & 63;
  const int wv   = tid >> 6;   // 0..3

  // ---- Phase 1: normalize -> bf16, MFMA-fragment order (10 rows/wave) ----
  {
    const int row0 = (blockIdx.x * 4 + wv) * 10;   // 2048 waves * 10 = 20480
    const int nL   = B * LQ;                       // 4096
    float2 v[10];
#pragma unroll
    for (int t = 0; t < 10; ++t) {
      int row = row0 + t;
      const float* src = (row < nL) ? left + (size_t)row * D
                                    : right + (size_t)(row - nL) * D;
      v[t] = *reinterpret_cast<const float2*>(src + lane * 2);
    }
    const unsigned lslot =
        (lane >> 3) * 1024u + ((lane >> 2) & 1) * 512u + (lane & 3) * 4u;
#pragma unroll
    for (int t = 0; t < 10; ++t) {
      int row = row0 + t;
      float ss = v[t].x * v[t].x + v[t].y * v[t].y;
#pragma unroll
      for (int off = 1; off < 64; off <<= 1) ss += __shfl_xor(ss, off);
      float inv = 1.0f / fmaxf(sqrtf(ss), 1e-12f);
      unsigned packed = (unsigned)f2bf_rne(v[t].x * inv) |
                        ((unsigned)f2bf_rne(v[t].y * inv) << 16);
      char* dst;
      if (row < nL) {
        dst = lbf + (row >> 5) * 8192 + (row & 31) * 16;
      } else {
        int r2 = row - nL;
        dst = rbf + (r2 >> 7) * 32768 + ((r2 >> 5) & 3) * 8192 + (r2 & 31) * 16;
      }
      *reinterpret_cast<unsigned*>(dst + lslot) = packed;
    }
  }
  gbar(syncp, NBLK);

  // ---- Phase 2: maxsim (round-5 body, verified) ---------------------------
  {
    const int xg = blockIdx.x >> 5;   // 0..15
    const int yg = blockIdx.x & 31;   // 0..31
    const int x0 = xg * 8 + wv * 2;
    const int lane16 = lane * 16;

    bf16x8 bfr[2][8];
#pragma unroll
    for (int xi = 0; xi < 2; ++xi)
#pragma unroll
      for (int ks = 0; ks < 8; ++ks)
        bfr[xi][ks] = *reinterpret_cast<const bf16x8*>(
            lbf + (x0 + xi) * 8192 + ks * 1024 + lane16);

    f32x16 z;
#pragma unroll
    for (int t = 0; t < 16; ++t) z[t] = 0.f;

    const char* rb0 = rbf + (size_t)(yg * YPB) * 32768;

#define LOADA(dst, s_next)                                                   \
  {                                                                          \
    const char* nb = rb0 + ((s_next) >> 2) * 32768 + ((s_next) & 3) * 8192;  \
    _Pragma("unroll")                                                        \
    for (int ks = 0; ks < 8; ++ks)                                           \
      dst[ks] = *reinterpret_cast<const bf16x8*>(nb + ks * 1024 + lane16);   \
  }

#define MFMAB(srcA)                                                          \
  __builtin_amdgcn_s_setprio(1);                                             \
  a0 = __builtin_amdgcn_mfma_f32_32x32x16_bf16(srcA[0], bfr[0][0], z, 0, 0, 0); \
  a1 = __builtin_amdgcn_mfma_f32_32x32x16_bf16(srcA[0], bfr[1][0], z, 0, 0, 0); \
  _Pragma("unroll")                                                          \
  for (int ks = 1; ks < 8; ++ks) {                                           \
    a0 = __builtin_amdgcn_mfma_f32_32x32x16_bf16(srcA[ks], bfr[0][ks], a0, 0, 0, 0); \
    a1 = __builtin_amdgcn_mfma_f32_32x32x16_bf16(srcA[ks], bfr[1][ks], a1, 0, 0, 0); \
  }                                                                          \
  __builtin_amdgcn_s_setprio(0);

    bf16x8 pA[8], pB[8];
    LOADA(pA, 0);

#pragma unroll
    for (int yy = 0; yy < YPB; ++yy) {
      float cm0 = -3.0e38f, cm1 = -3.0e38f;
#pragma unroll
      for (int mj = 0; mj < 4; ++mj) {
        const int s = yy * 4 + mj;     // compile-time after unroll
        f32x16 a0, a1;
        if ((s & 1) == 0) {
          if (s < 15) LOADA(pB, s + 1);
          MFMAB(pA);
        } else {
          if (s < 15) LOADA(pA, s + 1);
          MFMAB(pB);
        }
#pragma unroll
        for (int t = 0; t < 16; t += 4) {
          cm0 = fmaxf(cm0, fmaxf(fmaxf(a0[t], a0[t + 1]), fmaxf(a0[t + 2], a0[t + 3])));
          cm1 = fmaxf(cm1, fmaxf(fmaxf(a1[t], a1[t + 1]), fmaxf(a1[t + 2], a1[t + 3])));
        }
      }
      cm0 = fmaxf(cm0, __shfl_xor(cm0, 32));
      cm1 = fmaxf(cm1, __shfl_xor(cm1, 32));
#pragma unroll
      for (int off = 1; off <= 16; off <<= 1) {
        cm0 += __shfl_xor(cm0, off);
        cm1 += __shfl_xor(cm1, off);
      }
      if (lane == 0) {
        const int y = yg * YPB + yy;
        sims[(x0 + 0) * B + y] = cm0;
        sims[(x0 + 1) * B + y] = cm1;
      }
    }
#undef LOADA
#undef MFMAB
  }
  gbar(syncp + 32, NBLK);   // separate cache line

  // ---- Phase 3: CE loss, entirely in block 0 (4 waves x 32 rows) ----------
  if (blockIdx.x == 0) {
    const float scale = expf(ls[0]);
    float local = 0.f;
    for (int rr2 = 0; rr2 < 32; ++rr2) {
      const int x = wv * 32 + rr2;
      const float* row = sims + x * B;
      float a = row[lane], b2 = row[64 + lane];
      float m = fmaxf(a, b2);
#pragma unroll
      for (int off = 1; off < 64; off <<= 1) m = fmaxf(m, __shfl_xor(m, off));
      float ml = scale * m;
      float e = expf(scale * a - ml) + expf(scale * b2 - ml);
#pragma unroll
      for (int off = 1; off < 64; off <<= 1) e += __shfl_xor(e, off);
      int p = pos[x];
      float pv = __shfl(p < 64 ? a : b2, p & 63);
      local += -(scale * pv - ml - logf(e));
    }
    if (lane == 0) shred[wv] = local;
    __syncthreads();
    if (tid == 0)
      out[0] = (shred[0] + shred[1] + shred[2] + shred[3]) * (1.0f / (float)B);
  }
}

extern "C" void kernel_launch(void* const* d_in, const int* in_sizes, int n_in,
                              void* d_out, int out_size, void* d_ws, size_t ws_size,
                              hipStream_t stream) {
  const float* left  = (const float*)d_in[0];
  const float* right = (const float*)d_in[1];
  const float* ls    = (const float*)d_in[2];
  const int*   pos   = (const int*)d_in[3];
  float* out = (float*)d_out;

  char* ws  = (char*)d_ws;
  char* lbf = ws;                                        // 1 MiB
  char* rbf = ws + (size_t)(1 << 20);                    // 4 MiB
  float* sims = (float*)(ws + (size_t)(5 << 20));        // 64 KiB
  unsigned* syncp = (unsigned*)(ws + (size_t)(5 << 20) + 65536);

  hipMemsetAsync(syncp, 0, 256, stream);                 // reset barrier counters
  fused_kernel<<<NBLK, 256, 0, stream>>>(left, right, ls, pos, out,
                                         lbf, rbf, sims, syncp);
}

// Round 9
// 204.584 us; speedup vs baseline: 1.2242x; 1.2242x over previous
//
#include <hip/hip_runtime.h>
#include <hip/hip_bf16.h>

typedef short bf16x8 __attribute__((ext_vector_type(8)));
typedef float f32x16 __attribute__((ext_vector_type(16)));
typedef unsigned short u16;

#define B 128
#define LQ 32
#define LK 128
#define D 128
#define YPB 4
#define NBLK 512

// ws layout:
//   lbf : fragment-ordered l  (1 MiB @ 0)
//   rbf : fragment-ordered r  (4 MiB @ 1M)
//   sims: B*B f32 (64 KiB @ 5M)
//   nll : B f32 (@5M+64K+1K)
//   sync: c0 @ +0, d1 @ +128, d2 @ +256 of (5M+64K); memset 512B per call
// 32x32x16 MFMA fragment: lane = hh*32 + rr holds 8 elems, k = ks*16+hh*8+e;
// rr = A-row / B-col. Verified rounds 3-5/8 (absmax 0).

static __device__ inline u16 f2bf_rne(float f) {
  union { float f; unsigned u; } v; v.f = f;
  unsigned r = v.u + 0x7fffu + ((v.u >> 16) & 1u);
  return (u16)(r >> 16);
}

static __device__ inline unsigned aload(unsigned* p) {
  return __hip_atomic_load(p, __ATOMIC_RELAXED, __HIP_MEMORY_SCOPE_AGENT);
}
static __device__ inline unsigned aadd(unsigned* p) {
  return __hip_atomic_fetch_add(p, 1u, __ATOMIC_ACQ_REL,
                                __HIP_MEMORY_SCOPE_AGENT);
}

__global__ __launch_bounds__(256, 2) void fused_kernel(
    const float* __restrict__ left, const float* __restrict__ right,
    const float* __restrict__ ls, const int* __restrict__ pos,
    float* __restrict__ out, char* __restrict__ lbf, char* __restrict__ rbf,
    float* __restrict__ sims, float* __restrict__ nll,
    unsigned* __restrict__ syncp) {
  __shared__ float sred[4];
  __shared__ int swin;
  const int tid  = threadIdx.x;
  const int lane = tid & 63;
  const int wv   = tid >> 6;   // 0..3

  // ---- Phase 1: normalize -> bf16, MFMA-fragment order (10 rows/wave) ----
  {
    const int row0 = (blockIdx.x * 4 + wv) * 10;   // 2048 waves * 10 = 20480
    const int nL   = B * LQ;                       // 4096
    float2 v[10];
#pragma unroll
    for (int t = 0; t < 10; ++t) {
      int row = row0 + t;
      const float* src = (row < nL) ? left + (size_t)row * D
                                    : right + (size_t)(row - nL) * D;
      v[t] = *reinterpret_cast<const float2*>(src + lane * 2);
    }
    const unsigned lslot =
        (lane >> 3) * 1024u + ((lane >> 2) & 1) * 512u + (lane & 3) * 4u;
#pragma unroll
    for (int t = 0; t < 10; ++t) {
      int row = row0 + t;
      float ss = v[t].x * v[t].x + v[t].y * v[t].y;
#pragma unroll
      for (int off = 1; off < 64; off <<= 1) ss += __shfl_xor(ss, off);
      float inv = 1.0f / fmaxf(sqrtf(ss), 1e-12f);
      unsigned packed = (unsigned)f2bf_rne(v[t].x * inv) |
                        ((unsigned)f2bf_rne(v[t].y * inv) << 16);
      char* dst;
      if (row < nL) {
        dst = lbf + (row >> 5) * 8192 + (row & 31) * 16;
      } else {
        int r2 = row - nL;
        dst = rbf + (r2 >> 7) * 32768 + ((r2 >> 5) & 3) * 8192 + (r2 & 31) * 16;
      }
      *reinterpret_cast<unsigned*>(dst + lslot) = packed;
    }
  }
  // ---- grid barrier (arrive: RMW once; poll: relaxed LOADS, no RMW) ------
  __threadfence();
  __syncthreads();
  if (tid == 0) {
    aadd(syncp);
    while (aload(syncp) < NBLK) __builtin_amdgcn_s_sleep(2);
  }
  __syncthreads();
  __threadfence();

  // ---- Phase 2: maxsim (round-5 body, verified) ---------------------------
  {
    const int xg = blockIdx.x >> 5;   // 0..15
    const int yg = blockIdx.x & 31;   // 0..31
    const int x0 = xg * 8 + wv * 2;
    const int lane16 = lane * 16;

    bf16x8 bfr[2][8];
#pragma unroll
    for (int xi = 0; xi < 2; ++xi)
#pragma unroll
      for (int ks = 0; ks < 8; ++ks)
        bfr[xi][ks] = *reinterpret_cast<const bf16x8*>(
            lbf + (x0 + xi) * 8192 + ks * 1024 + lane16);

    f32x16 z;
#pragma unroll
    for (int t = 0; t < 16; ++t) z[t] = 0.f;

    const char* rb0 = rbf + (size_t)(yg * YPB) * 32768;

#define LOADA(dst, s_next)                                                   \
  {                                                                          \
    const char* nb = rb0 + ((s_next) >> 2) * 32768 + ((s_next) & 3) * 8192;  \
    _Pragma("unroll")                                                        \
    for (int ks = 0; ks < 8; ++ks)                                           \
      dst[ks] = *reinterpret_cast<const bf16x8*>(nb + ks * 1024 + lane16);   \
  }

#define MFMAB(srcA)                                                          \
  __builtin_amdgcn_s_setprio(1);                                             \
  a0 = __builtin_amdgcn_mfma_f32_32x32x16_bf16(srcA[0], bfr[0][0], z, 0, 0, 0); \
  a1 = __builtin_amdgcn_mfma_f32_32x32x16_bf16(srcA[0], bfr[1][0], z, 0, 0, 0); \
  _Pragma("unroll")                                                          \
  for (int ks = 1; ks < 8; ++ks) {                                           \
    a0 = __builtin_amdgcn_mfma_f32_32x32x16_bf16(srcA[ks], bfr[0][ks], a0, 0, 0, 0); \
    a1 = __builtin_amdgcn_mfma_f32_32x32x16_bf16(srcA[ks], bfr[1][ks], a1, 0, 0, 0); \
  }                                                                          \
  __builtin_amdgcn_s_setprio(0);

    bf16x8 pA[8], pB[8];
    LOADA(pA, 0);

#pragma unroll
    for (int yy = 0; yy < YPB; ++yy) {
      float cm0 = -3.0e38f, cm1 = -3.0e38f;
#pragma unroll
      for (int mj = 0; mj < 4; ++mj) {
        const int s = yy * 4 + mj;     // compile-time after unroll
        f32x16 a0, a1;
        if ((s & 1) == 0) {
          if (s < 15) LOADA(pB, s + 1);
          MFMAB(pA);
        } else {
          if (s < 15) LOADA(pA, s + 1);
          MFMAB(pB);
        }
#pragma unroll
        for (int t = 0; t < 16; t += 4) {
          cm0 = fmaxf(cm0, fmaxf(fmaxf(a0[t], a0[t + 1]), fmaxf(a0[t + 2], a0[t + 3])));
          cm1 = fmaxf(cm1, fmaxf(fmaxf(a1[t], a1[t + 1]), fmaxf(a1[t + 2], a1[t + 3])));
        }
      }
      cm0 = fmaxf(cm0, __shfl_xor(cm0, 32));
      cm1 = fmaxf(cm1, __shfl_xor(cm1, 32));
#pragma unroll
      for (int off = 1; off <= 16; off <<= 1) {
        cm0 += __shfl_xor(cm0, off);
        cm1 += __shfl_xor(cm1, off);
      }
      if (lane == 0) {
        const int y = yg * YPB + yy;
        sims[(x0 + 0) * B + y] = cm0;
        sims[(x0 + 1) * B + y] = cm1;
      }
    }
#undef LOADA
#undef MFMAB
  }

  // ---- arrive phase-2-done; blocks >= B exit ------------------------------
  __threadfence();
  __syncthreads();
  unsigned* d1 = syncp + 32;
  unsigned* d2 = syncp + 64;
  if (tid == 0) aadd(d1);
  if (blockIdx.x >= B) return;

  if (tid == 0) {
    while (aload(d1) < NBLK) __builtin_amdgcn_s_sleep(2);
  }
  __syncthreads();
  __threadfence();

  // ---- Phase 3: one CE row per block (blocks 0..127) ----------------------
  {
    const int x = blockIdx.x;
    const float scale = expf(ls[0]);
    float a = (tid < B) ? sims[x * B + tid] : -3.0e38f;
    float m = a;
#pragma unroll
    for (int off = 1; off < 64; off <<= 1) m = fmaxf(m, __shfl_xor(m, off));
    if (lane == 0) sred[wv] = m;
    __syncthreads();
    const float M =
        fmaxf(fmaxf(sred[0], sred[1]), fmaxf(sred[2], sred[3])) * scale;
    __syncthreads();
    float e = (tid < B) ? expf(scale * a - M) : 0.0f;
#pragma unroll
    for (int off = 1; off < 64; off <<= 1) e += __shfl_xor(e, off);
    if (lane == 0) sred[wv] = e;
    __syncthreads();
    if (tid == 0) {
      float S = sred[0] + sred[1] + sred[2] + sred[3];
      float pv = sims[x * B + pos[x]];
      nll[x] = -(scale * pv - M - logf(S));
      __threadfence();
      unsigned old = aadd(d2);
      swin = (old == B - 1) ? 1 : 0;
    }
    __syncthreads();
  }

  // ---- Phase 4: winner block sums nll ------------------------------------
  if (swin) {
    __threadfence();
    if (tid < 64) {
      float vsum = nll[tid] + nll[tid + 64];
#pragma unroll
      for (int off = 1; off < 64; off <<= 1) vsum += __shfl_xor(vsum, off);
      if (tid == 0) out[0] = vsum * (1.0f / (float)B);
    }
  }
}

extern "C" void kernel_launch(void* const* d_in, const int* in_sizes, int n_in,
                              void* d_out, int out_size, void* d_ws, size_t ws_size,
                              hipStream_t stream) {
  const float* left  = (const float*)d_in[0];
  const float* right = (const float*)d_in[1];
  const float* ls    = (const float*)d_in[2];
  const int*   pos   = (const int*)d_in[3];
  float* out = (float*)d_out;

  char* ws  = (char*)d_ws;
  char* lbf = ws;                                        // 1 MiB
  char* rbf = ws + (size_t)(1 << 20);                    // 4 MiB
  float* sims = (float*)(ws + (size_t)(5 << 20));        // 64 KiB
  unsigned* syncp = (unsigned*)(ws + (size_t)(5 << 20) + 65536);
  float* nll = (float*)(ws + (size_t)(5 << 20) + 65536 + 1024);

  hipMemsetAsync(syncp, 0, 512, stream);                 // reset sync counters
  fused_kernel<<<NBLK, 256, 0, stream>>>(left, right, ls, pos, out,
                                         lbf, rbf, sims, nll, syncp);
}

// Round 10
// 34.958 us; speedup vs baseline: 7.1644x; 5.8523x over previous
//
#include <hip/hip_runtime.h>
#include <hip/hip_bf16.h>

typedef short bf16x8 __attribute__((ext_vector_type(8)));
typedef float f32x16 __attribute__((ext_vector_type(16)));
typedef unsigned short u16;

#define B 128
#define LQ 32
#define LK 128
#define D 128

// ws layout:
//   lbf : fragment-ordered l, [x][ks(8)][hh(2)][rr(32)] x 16B  (1 MiB @ 0)
//   rbf : fragment-ordered r, [y][mj(4)][ks(8)][hh(2)][rr(32)] x 16B (4 MiB @ 1M)
//   sims: B*B f32 (64 KiB @ 5M)
// 32x32x16 MFMA fragment: lane = hh*32 + rr holds 8 elems, k = ks*16+hh*8+e;
// rr = A-row / B-col. Verified rounds 3-5/8/9 (absmax 0).

static __device__ inline u16 f2bf_rne(float f) {
  union { float f; unsigned u; } v; v.f = f;
  unsigned r = v.u + 0x7fffu + ((v.u >> 16) & 1u);
  return (u16)(r >> 16);
}

// One wave per row. Normalize, cast to bf16, store in MFMA-fragment order.
__global__ __launch_bounds__(256) void normalize_kernel(
    const float* __restrict__ left, const float* __restrict__ right,
    char* __restrict__ lbf, char* __restrict__ rbf) {
  int wave = (blockIdx.x * blockDim.x + threadIdx.x) >> 6;
  int lane = threadIdx.x & 63;
  const int n_l = B * LQ;
  const float* src; char* dst;
  if (wave < n_l) {
    src = left + (size_t)wave * D;
    dst = lbf + (wave >> 5) * 8192 + (wave & 31) * 16;
  } else {
    int row = wave - n_l;
    src = right + (size_t)row * D;
    dst = rbf + (row >> 7) * 32768 + ((row >> 5) & 3) * 8192 + (row & 31) * 16;
  }
  float2 v = *reinterpret_cast<const float2*>(src + lane * 2);
  float ss = v.x * v.x + v.y * v.y;
#pragma unroll
  for (int off = 1; off < 64; off <<= 1) ss += __shfl_xor(ss, off);
  float inv = 1.0f / fmaxf(sqrtf(ss), 1e-12f);
  unsigned packed = (unsigned)f2bf_rne(v.x * inv) |
                    ((unsigned)f2bf_rne(v.y * inv) << 16);
  *reinterpret_cast<unsigned*>(
      dst + (lane >> 3) * 1024 + ((lane >> 2) & 1) * 512 + (lane & 3) * 4) = packed;
}

// Per (x,y): T[j][i] = sum_k r[y][j][k]*l[x][i][k] via 32x32x16 bf16 MFMA;
// sim[x][y] = sum_i max_j T. Fragment-ordered inputs -> every load is a
// contiguous 1KB wave load. DEPTH-3 rotating prefetch (p0/p1/p2): at step s,
// prefetch tile s+2 while MFMAing tile s -> 16-24 loads in flight per wave.
// Grid 16 xg * 32 yg = 512 blocks, 4 waves (wave = 2 x's), 4 y per block.
__global__ __launch_bounds__(256, 2) void maxsim_kernel(
    const char* __restrict__ lbf, const char* __restrict__ rbf,
    float* __restrict__ sims) {
  const int lane = threadIdx.x & 63;
  const int wv   = threadIdx.x >> 6;   // 0..3
  const int xg   = blockIdx.x >> 5;    // 0..15
  const int yg   = blockIdx.x & 31;    // 0..31
  const int x0   = xg * 8 + wv * 2;
  const int lane16 = lane * 16;

  // B fragments for 2 x's: 16 contiguous 1KB loads.
  bf16x8 bfr[2][8];
#pragma unroll
  for (int xi = 0; xi < 2; ++xi)
#pragma unroll
    for (int ks = 0; ks < 8; ++ks)
      bfr[xi][ks] = *reinterpret_cast<const bf16x8*>(
          lbf + (x0 + xi) * 8192 + ks * 1024 + lane16);

  f32x16 z;
#pragma unroll
  for (int t = 0; t < 16; ++t) z[t] = 0.f;

  // r subtiles for this block are contiguous: tile s (s = yy*4+mj) at s*8192.
  const char* rb0 = rbf + (size_t)(yg * 4) * 32768;

#define LOADA(dst, s_next)                                                   \
  {                                                                          \
    const char* nb = rb0 + (s_next) * 8192;                                  \
    _Pragma("unroll")                                                        \
    for (int ks = 0; ks < 8; ++ks)                                           \
      dst[ks] = *reinterpret_cast<const bf16x8*>(nb + ks * 1024 + lane16);   \
  }

#define MFMAB(srcA)                                                          \
  __builtin_amdgcn_s_setprio(1);                                             \
  a0 = __builtin_amdgcn_mfma_f32_32x32x16_bf16(srcA[0], bfr[0][0], z, 0, 0, 0); \
  a1 = __builtin_amdgcn_mfma_f32_32x32x16_bf16(srcA[0], bfr[1][0], z, 0, 0, 0); \
  _Pragma("unroll")                                                          \
  for (int ks = 1; ks < 8; ++ks) {                                           \
    a0 = __builtin_amdgcn_mfma_f32_32x32x16_bf16(srcA[ks], bfr[0][ks], a0, 0, 0, 0); \
    a1 = __builtin_amdgcn_mfma_f32_32x32x16_bf16(srcA[ks], bfr[1][ks], a1, 0, 0, 0); \
  }                                                                          \
  __builtin_amdgcn_s_setprio(0);

#define FOLD()                                                               \
  _Pragma("unroll")                                                          \
  for (int t = 0; t < 16; t += 4) {                                          \
    cm0 = fmaxf(cm0, fmaxf(fmaxf(a0[t], a0[t + 1]), fmaxf(a0[t + 2], a0[t + 3]))); \
    cm1 = fmaxf(cm1, fmaxf(fmaxf(a1[t], a1[t + 1]), fmaxf(a1[t + 2], a1[t + 3]))); \
  }

#define STEP(s, CUR, PF)                                                     \
  if ((s) + 2 < 16) LOADA(PF, (s) + 2);                                      \
  MFMAB(CUR);                                                                \
  FOLD();

#define EPI(yy)                                                              \
  cm0 = fmaxf(cm0, __shfl_xor(cm0, 32));                                     \
  cm1 = fmaxf(cm1, __shfl_xor(cm1, 32));                                     \
  _Pragma("unroll")                                                          \
  for (int off = 1; off <= 16; off <<= 1) {                                  \
    cm0 += __shfl_xor(cm0, off);                                             \
    cm1 += __shfl_xor(cm1, off);                                             \
  }                                                                          \
  if (lane == 0) {                                                           \
    sims[(x0 + 0) * B + (yg * 4 + (yy))] = cm0;                              \
    sims[(x0 + 1) * B + (yg * 4 + (yy))] = cm1;                              \
  }

  bf16x8 p0[8], p1[8], p2[8];
  f32x16 a0, a1;
  float cm0, cm1;

  LOADA(p0, 0);
  LOADA(p1, 1);

  cm0 = cm1 = -3.0e38f;
  STEP(0,  p0, p2); STEP(1,  p1, p0); STEP(2,  p2, p1); STEP(3,  p0, p2);
  EPI(0);
  cm0 = cm1 = -3.0e38f;
  STEP(4,  p1, p0); STEP(5,  p2, p1); STEP(6,  p0, p2); STEP(7,  p1, p0);
  EPI(1);
  cm0 = cm1 = -3.0e38f;
  STEP(8,  p2, p1); STEP(9,  p0, p2); STEP(10, p1, p0); STEP(11, p2, p1);
  EPI(2);
  cm0 = cm1 = -3.0e38f;
  STEP(12, p0, p2); STEP(13, p1, p0); STEP(14, p2, p1); STEP(15, p0, p1);
  EPI(3);

#undef LOADA
#undef MFMAB
#undef FOLD
#undef STEP
#undef EPI
}

// log-softmax + CE. 1 block, 1024 threads = 16 waves; wave w -> rows w*8..+7.
__global__ __launch_bounds__(1024) void loss_kernel(
    const float* __restrict__ sims, const float* __restrict__ logit_scale,
    const int* __restrict__ pos_idx, float* __restrict__ out) {
  __shared__ float red[16];
  const int lane = threadIdx.x & 63;
  const int wv   = threadIdx.x >> 6;
  const float scale = expf(logit_scale[0]);
  float local = 0.f;
#pragma unroll
  for (int rr = 0; rr < 8; ++rr) {
    const int x = wv * 8 + rr;
    const float* row = sims + x * B;
    float a = row[lane], b2 = row[64 + lane];
    float m = fmaxf(a, b2);
#pragma unroll
    for (int off = 1; off < 64; off <<= 1) m = fmaxf(m, __shfl_xor(m, off));
    float ml = scale * m;
    float e = expf(scale * a - ml) + expf(scale * b2 - ml);
#pragma unroll
    for (int off = 1; off < 64; off <<= 1) e += __shfl_xor(e, off);
    int pos = pos_idx[x];
    float pv = __shfl(pos < 64 ? a : b2, pos & 63);
    local += -(scale * pv - ml - logf(e));
  }
  if (lane == 0) red[wv] = local;
  __syncthreads();
  if (threadIdx.x == 0) {
    float t = 0.f;
#pragma unroll
    for (int i = 0; i < 16; ++i) t += red[i];
    out[0] = t / (float)B;
  }
}

extern "C" void kernel_launch(void* const* d_in, const int* in_sizes, int n_in,
                              void* d_out, int out_size, void* d_ws, size_t ws_size,
                              hipStream_t stream) {
  const float* left  = (const float*)d_in[0];
  const float* right = (const float*)d_in[1];
  const float* ls    = (const float*)d_in[2];
  const int*   pos   = (const int*)d_in[3];
  float* out = (float*)d_out;

  char* ws  = (char*)d_ws;
  char* lbf = ws;                                   // 1 MiB
  char* rbf = ws + (size_t)(1 << 20);               // 4 MiB
  float* sims = (float*)(ws + (size_t)(5 << 20));   // 64 KiB

  int waves = B * LQ + B * LK;  // 20480 rows
  normalize_kernel<<<waves / 4, 256, 0, stream>>>(left, right, lbf, rbf);
  maxsim_kernel<<<512, 256, 0, stream>>>(lbf, rbf, sims);
  loss_kernel<<<1, 1024, 0, stream>>>(sims, ls, pos, out);
}